// Round 4
// baseline (200.839 us; speedup 1.0000x reference)
//
#include <hip/hip_runtime.h>
#include <stdint.h>

// x: [B=8, L=131072, C=16] f32, integer values in [0,5). K=9, pad_l=3, pad_r=4
// -> output length L-1. Outputs (soft-argmax, density) each [B, L-1, C] f32,
// concatenated flat in d_out.
constexpr int Bn   = 8;
constexpr int Ln   = 131072;
constexpr int Cn   = 16;
constexpr int Lout = Ln - 1;                  // 131071
constexpr int Tn   = 8;                       // outputs per thread (per channel group)
constexpr int NCHUNK = (Lout + Tn - 1) / Tn;  // 16384
constexpr int CG   = Cn / 4;                  // 4 channel-groups of float4

typedef float f4 __attribute__((ext_vector_type(4)));  // native vector: nt-store OK

// packed 4x8-bit count increment for values 1..4; v==0 -> 0.
__device__ __forceinline__ uint32_t inc_of(int v) {
    return (uint32_t)((1ull << (v * 8)) >> 8);
}

__global__ __launch_bounds__(256, 4)
void mop_kernel(const f4* __restrict__ x, f4* __restrict__ outp) {
    f4* dens = outp + (size_t)Bn * Lout * CG;

    int t     = blockIdx.x * 256 + threadIdx.x;
    int g     = t & (CG - 1);                 // 4 consecutive lanes = 16 channels = 64B
    int chunk = (t >> 2) & (NCHUNK - 1);
    int b     = t >> 16;                      // / (CG * NCHUNK)

    const f4* xb = x    + ((size_t)b * Ln)   * CG + g;
    f4*       ob = outp + ((size_t)b * Lout) * CG + g;
    f4*       db = dens + ((size_t)b * Lout) * CG + g;
    int l0 = chunk * Tn;

    uint32_t cnt[4]  = {0, 0, 0, 0};   // per-channel packed counts of values 1..4
    uint32_t hist[4] = {0, 0, 0, 0};   // per-channel 9x3-bit value history

    // Window for output l covers original positions [l-3, l+5]; init for l=l0.
    #pragma unroll
    for (int o = -3; o <= 5; ++o) {
        int p = l0 + o;
        f4 vv = (f4)0.f;
        if (p >= 0 && p < Ln) vv = xb[(size_t)p * CG];
        int va[4] = {(int)vv.x, (int)vv.y, (int)vv.z, (int)vv.w};
        #pragma unroll
        for (int j = 0; j < 4; ++j) {
            cnt[j]  += inc_of(va[j]);
            hist[j]  = ((hist[j] << 3) | (uint32_t)va[j]) & 0x7FFFFFFu;
        }
    }

    // Fully unrolled: all 8 prefetch loads are address-independent of the
    // loop-carried state, so the compiler hoists them ahead of the chain.
    #pragma unroll
    for (int i = 0; i < Tn; ++i) {
        int l = l0 + i;

        int pa = l + 6;
        f4 vv = (f4)0.f;
        if (pa < Ln) vv = xb[(size_t)pa * CG];

        float ov[4], dv[4];
        #pragma unroll
        for (int j = 0; j < 4; ++j) {
            uint32_t cw = cnt[j];
            int c1 = cw & 255, c2 = (cw >> 8) & 255, c3 = (cw >> 16) & 255, c4 = cw >> 24;
            int m = max(max(c1, c2), max(c3, c4));
            // tie-averaged argmax over bins 1..4 (softmax@1e10 == 1/n per max bin)
            int n = (c1 == m) + (c2 == m) + (c3 == m) + (c4 == m);
            int s = (c1 == m) + 2 * (c2 == m) + 3 * (c3 == m) + 4 * (c4 == m);
            float r = __builtin_amdgcn_rcpf((float)n);   // exact for 1,2,4; ~1e-7 for 3
            ov[j] = (m == 0) ? 0.0f : (float)s * r;
            dv[j] = (m == 0) ? 1.0f : (float)m;
        }

        if (l < Lout) {
            // zero-reuse outputs: bypass L2 (nt), keep L2 for input halos
            f4 o4 = {ov[0], ov[1], ov[2], ov[3]};
            f4 d4 = {dv[0], dv[1], dv[2], dv[3]};
            __builtin_nontemporal_store(o4, &ob[(size_t)l * CG]);
            __builtin_nontemporal_store(d4, &db[(size_t)l * CG]);
        }

        int va[4] = {(int)vv.x, (int)vv.y, (int)vv.z, (int)vv.w};
        #pragma unroll
        for (int j = 0; j < 4; ++j) {
            int vr = (hist[j] >> 24) & 7;
            cnt[j] += inc_of(va[j]) - inc_of(vr);
            hist[j] = ((hist[j] << 3) | (uint32_t)va[j]) & 0x7FFFFFFu;
        }
    }
}

extern "C" void kernel_launch(void* const* d_in, const int* in_sizes, int n_in,
                              void* d_out, int out_size, void* d_ws, size_t ws_size,
                              hipStream_t stream) {
    const f4* x = (const f4*)d_in[0];
    f4* outp = (f4*)d_out;
    constexpr int total_threads = Bn * CG * NCHUNK;  // 524288
    mop_kernel<<<total_threads / 256, 256, 0, stream>>>(x, outp);
}

// Round 5
// 185.620 us; speedup vs baseline: 1.0820x; 1.0820x over previous
//
#include <hip/hip_runtime.h>
#include <stdint.h>

// x: [B=8, L=131072, C=16] f32, integer values in [0,5). K=9, pad_l=3, pad_r=4
// -> output length L-1 = 131071. Outputs (soft-argmax, density) each
// [B, Lout, C] f32, concatenated flat in d_out.
//
// Structure: wave-coalesced prefix-scan. Lane = (k,g): k = lane&15 is the
// l-position within a 16-wide block, g = lane>>4 the channel-quad. Every
// global load/store is one fully-contiguous 1KB block per wave (like the
// 6.7 TB/s fillBuffer stream). Window counts come from packed-byte prefix
// sums: W[l-3..l+5] = PS_cur-head + PS_prev-diff + tail-of-prev-prev,
// software-pipelined one block deep.
constexpr int Bn   = 8;
constexpr int Ln   = 131072;
constexpr int Cn   = 16;
constexpr int Lout = Ln - 1;
constexpr int CG   = Cn / 4;                // 4 f4 per l-position
constexpr int NBLK = (Lout + 15) / 16;      // 8192 output blocks of 16 per b
constexpr int ITER = 8;                     // output blocks per wave
constexpr int SPANS = NBLK / ITER;          // 1024 spans per b

typedef float f4 __attribute__((ext_vector_type(4)));

// packed 4x8-bit increment for values 1..4; v==0 -> 0.
__device__ __forceinline__ uint32_t inc_of(int v) {
    return (uint32_t)((1ull << (v * 8)) >> 8);
}

__global__ __launch_bounds__(256, 4)
void mop_kernel(const f4* __restrict__ x, f4* __restrict__ outp) {
    f4* dens = outp + (size_t)Bn * Lout * CG;

    const int lane = threadIdx.x & 63;
    const int k    = lane & 15;       // l offset within block
    const int g    = lane >> 4;       // channel quad
    const int w    = blockIdx.x * 4 + (threadIdx.x >> 6);
    const int b    = w >> 10;         // / SPANS (1024)
    const int span = w & (SPANS - 1);
    const int B0   = span * ITER;     // first output block index

    const f4* xb = x    + (size_t)b * Ln   * CG;
    f4*       ob = outp + (size_t)b * Lout * CG;
    f4*       db = dens + (size_t)b * Lout * CG;

    uint32_t PSp[4] = {0, 0, 0, 0};   // scan of previous block (jo)
    uint32_t D1[4]  = {0, 0, 0, 0};   // tail-carry pipeline
    uint32_t D2[4]  = {0, 0, 0, 0};   // = T_{jo-1} - PS_{jo-1}(k+12), per-lane

    // preload block jc = B0-1 (it = 0)
    f4 vv = (f4)0.f;
    {
        int lc = (B0 - 1) * 16 + k;
        if (lc >= 0 && lc < Ln) vv = xb[(size_t)lc * CG + g];
    }

    #pragma unroll
    for (int it = 0; it <= ITER + 1; ++it) {
        // prefetch next block (address independent of scan state)
        f4 vn = (f4)0.f;
        if (it <= ITER) {
            int lc = (B0 + it) * 16 + k;
            if (lc < Ln) vn = xb[(size_t)lc * CG + g];  // lc >= 0 always here
        }

        // packed increments + inclusive scan over k (width-16 segments)
        uint32_t ps[4];
        int vi[4] = {(int)vv.x, (int)vv.y, (int)vv.z, (int)vv.w};
        #pragma unroll
        for (int c = 0; c < 4; ++c) ps[c] = inc_of(vi[c]);
        #pragma unroll
        for (int d = 1; d < 16; d <<= 1) {
            #pragma unroll
            for (int c = 0; c < 4; ++c) {
                uint32_t t = __shfl_up(ps[c], d, 16);
                if (k >= d) ps[c] += t;
            }
        }

        // output block jo = B0 + it - 2 (needs PSp = scan(jo), ps = scan(jo+1), D2)
        if (it >= 2) {
            int l = (B0 + it - 2) * 16 + k;
            float ov[4], dv[4];
            #pragma unroll
            for (int c = 0; c < 4; ++c) {
                uint32_t ehi = __shfl(PSp[c], (k <= 10) ? (k + 5) : 15, 16);
                uint32_t elo = __shfl(PSp[c], (k - 4) & 15, 16);
                elo = (k >= 4) ? elo : 0u;
                uint32_t Rp  = __shfl(ps[c], (k - 11) & 15, 16);
                Rp = (k > 10) ? Rp : 0u;
                uint32_t Lp  = (k < 3) ? D2[c] : 0u;
                uint32_t W = ehi - elo + Lp + Rp;   // packed window counts, bytes

                int c1 = W & 255, c2 = (W >> 8) & 255, c3 = (W >> 16) & 255, c4 = W >> 24;
                int m = max(max(c1, c2), max(c3, c4));
                int n = (c1 == m) + (c2 == m) + (c3 == m) + (c4 == m);
                int s = (c1 == m) + 2 * (c2 == m) + 3 * (c3 == m) + 4 * (c4 == m);
                float r = __builtin_amdgcn_rcpf((float)n);  // exact for 1,2,4; ~1e-7 for 3
                ov[c] = (m == 0) ? 0.0f : (float)s * r;
                dv[c] = (m == 0) ? 1.0f : (float)m;
            }
            if (l < Lout) {
                f4 o4 = {ov[0], ov[1], ov[2], ov[3]};
                f4 d4 = {dv[0], dv[1], dv[2], dv[3]};
                __builtin_nontemporal_store(o4, &ob[(size_t)l * CG + g]);
                __builtin_nontemporal_store(d4, &db[(size_t)l * CG + g]);
            }
        }

        // pipeline shift: D carries "tail of block" two stages; PSp one stage
        #pragma unroll
        for (int c = 0; c < 4; ++c) {
            uint32_t T  = __shfl(ps[c], 15, 16);
            uint32_t Dn = __shfl(T - ps[c], (k + 12) & 15, 16);  // sum pos k+13..15
            D2[c] = D1[c];
            D1[c] = Dn;
            PSp[c] = ps[c];
        }
        vv = vn;
    }
}

extern "C" void kernel_launch(void* const* d_in, const int* in_sizes, int n_in,
                              void* d_out, int out_size, void* d_ws, size_t ws_size,
                              hipStream_t stream) {
    const f4* x = (const f4*)d_in[0];
    f4* outp = (f4*)d_out;
    constexpr int n_waves  = Bn * SPANS;        // 8192
    constexpr int n_blocks = n_waves / 4;       // 2048 blocks of 256 threads
    mop_kernel<<<n_blocks, 256, 0, stream>>>(x, outp);
}